// Round 4
// baseline (1074.031 us; speedup 1.0000x reference)
//
#include <hip/hip_runtime.h>
#include <hip/hip_bf16.h>

// MSSA: x(8,2048,512) -> qkv = x@Wqkv ; scores = (q*s)@(k*s)^T over FULL 512 dims ;
// attn = softmax ; out = attn@v ; result = (out + x)@Wout + bout
// Workspace (67.1MB):
//   qkvb : bf16 [16384][1536]  q cols 0-511 (scaled 0.125), k cols 512-1023 (scaled),
//                              v cols 1024-1535 dead after transpose_v -> reused for res
//   VT   : bf16 [512][16384]   V transposed (d-major)

typedef __attribute__((ext_vector_type(8))) short bf16x8;
typedef __attribute__((ext_vector_type(4))) float f32x4;

__device__ __forceinline__ unsigned short f2bf(float f) {
  unsigned u = __builtin_bit_cast(unsigned, f);
  u += 0x7fffu + ((u >> 16) & 1u);   // RNE
  return (unsigned short)(u >> 16);
}

// ---------------- GEMM1: qkv = bf16(x) @ bf16(Wqkv), scale q,k cols by 0.125 ----------------
__global__ __launch_bounds__(256) void gemm_qkv(const float* __restrict__ X,
                                                const float* __restrict__ W,
                                                unsigned short* __restrict__ QKV) {
  __shared__ __align__(16) unsigned short Asm[64][40];
  __shared__ __align__(16) unsigned short Bsm[64][40];
  const int tid = threadIdx.x;
  const int wave = tid >> 6, lane = tid & 63;
  const int lg = lane >> 4, ll = lane & 15;
  const int kk = lg * 8;
  const int m0 = blockIdx.y * 64, n0 = blockIdx.x * 64;

  f32x4 acc[4];
#pragma unroll
  for (int i = 0; i < 4; ++i) acc[i] = (f32x4){0.f, 0.f, 0.f, 0.f};

  const int arow = wave * 16 + ll;

  for (int kt = 0; kt < 512; kt += 32) {
    {
      const int row = tid >> 2, k0 = (tid & 3) * 8;
      const float* src = X + (size_t)(m0 + row) * 512 + kt + k0;
      bf16x8 v;
#pragma unroll
      for (int i = 0; i < 8; ++i) v[i] = (short)f2bf(src[i]);
      *(bf16x8*)&Asm[row][k0] = v;
    }
    {
      const int k = tid >> 3, cl = tid & 7;
      const float* src = W + (size_t)(kt + k) * 1536 + n0 + cl;
#pragma unroll
      for (int i = 0; i < 8; ++i) Bsm[cl + i * 8][k] = f2bf(src[i * 8]);
    }
    __syncthreads();
    bf16x8 a = *(const bf16x8*)&Asm[arow][kk];
#pragma unroll
    for (int nf = 0; nf < 4; ++nf) {
      bf16x8 b = *(const bf16x8*)&Bsm[nf * 16 + ll][kk];
      acc[nf] = __builtin_amdgcn_mfma_f32_16x16x32_bf16(a, b, acc[nf], 0, 0, 0);
    }
    __syncthreads();
  }
#pragma unroll
  for (int nf = 0; nf < 4; ++nf) {
    const int col = n0 + nf * 16 + ll;
    const float scl = (col < 1024) ? 0.125f : 1.0f;
#pragma unroll
    for (int r = 0; r < 4; ++r) {
      const int row = m0 + wave * 16 + lg * 4 + r;
      QKV[(size_t)row * 1536 + col] = f2bf(acc[nf][r] * scl);
    }
  }
}

// ---------------- Transpose V: VT[d][m] = qkv[m][1024+d] ----------------
__global__ __launch_bounds__(256) void transpose_v(const unsigned short* __restrict__ QKV,
                                                   unsigned short* __restrict__ VT) {
  const int t = threadIdx.x;
  const int m0 = blockIdx.x * 128 + (t & 15) * 8;
  const int d0 = blockIdx.y * 128 + (t >> 4) * 8;
  bf16x8 r[8];
#pragma unroll
  for (int j = 0; j < 8; ++j)
    r[j] = *(const bf16x8*)&QKV[(size_t)(m0 + j) * 1536 + 1024 + d0];
#pragma unroll
  for (int i = 0; i < 8; ++i) {
    bf16x8 o;
#pragma unroll
    for (int j = 0; j < 8; ++j) o[j] = r[j][i];
    *(bf16x8*)&VT[(size_t)(d0 + i) * 16384 + m0] = o;
  }
}

// ---------------- Flash attention + residual, 8 waves, in-block split-KV ----------------
// group g = wave>>2 processes KV tiles 2*mt+g; merge at end (flash state combine).
// __launch_bounds__(512, 1): 1 block/CU min -> VGPR cap 256 (R3's (512,2) capped at 128 -> spill)
__global__ __launch_bounds__(512, 1) void flash_attn(const unsigned short* __restrict__ QKV,
                                                     const unsigned short* __restrict__ VT,
                                                     const float* __restrict__ X,
                                                     unsigned short* __restrict__ RES) {
  // manual layout so the merge phase can overlay K/V as fp32 exchange space
  __shared__ __align__(16) unsigned short smem[79360];  // 158,720 B
  const int tid = threadIdx.x;
  const int wave = tid >> 6, lane = tid & 63;
  const int g = wave >> 2, wq = wave & 3;
  const int gtid = tid & 255;
  const int lg = lane >> 4, ll = lane & 15;
  const int kk = lg * 8;
  unsigned short* Ks = smem + g * 16640;           // [32][520]
  unsigned short* Vs = smem + 33280 + g * 20480;   // [512][40]
  unsigned short* Ps = smem + 74240 + wave * 640;  // [16][40]

  const int b = blockIdx.x, qt = blockIdx.y;  // linear%8 = b -> one batch per XCD
  const size_t qrow_base = (size_t)b * 2048 + qt * 64 + wq * 16;

  // Q fragments (A layout: row=lane&15, k=(lane>>4)*8+j)
  bf16x8 qf[16];
  {
    const size_t row = qrow_base + ll;
#pragma unroll
    for (int kb = 0; kb < 16; ++kb)
      qf[kb] = *(const bf16x8*)&QKV[row * 1536 + kb * 32 + kk];
  }

  const int krow = gtid >> 6, kin = (gtid & 63) * 8;
  const int vrow = gtid >> 2, vin = (gtid & 3) * 8;
  const unsigned short* Kg = QKV + ((size_t)b * 2048) * 1536 + 512;
  const unsigned short* Vg = VT + (size_t)b * 2048;

  bf16x8 kr[8], vr[8];
  {  // prefetch first tile of this group (tile index g)
    const size_t moff = (size_t)g * 32;
#pragma unroll
    for (int p = 0; p < 8; ++p) {
      kr[p] = *(const bf16x8*)&Kg[(moff + p * 4 + krow) * 1536 + kin];
      vr[p] = *(const bf16x8*)&Vg[(size_t)(p * 64 + vrow) * 16384 + moff + vin];
    }
  }

  f32x4 o[32];
#pragma unroll
  for (int i = 0; i < 32; ++i) o[i] = (f32x4){0.f, 0.f, 0.f, 0.f};
  float mrow[4] = {-1e30f, -1e30f, -1e30f, -1e30f};
  float lrow[4] = {0.f, 0.f, 0.f, 0.f};  // per-lane PARTIAL sum; reduced once at end

  for (int mt = 0; mt < 32; ++mt) {
    __syncthreads();
    {  // commit prefetched tile
#pragma unroll
      for (int p = 0; p < 8; ++p) {
        *(bf16x8*)&Ks[(p * 4 + krow) * 520 + kin] = kr[p];
        *(bf16x8*)&Vs[(p * 64 + vrow) * 40 + vin] = vr[p];
      }
    }
    __syncthreads();
    if (mt < 31) {  // T14: issue next-tile loads; latency hides under QK+softmax+PV
      const size_t moff = (size_t)(2 * (mt + 1) + g) * 32;
#pragma unroll
      for (int p = 0; p < 8; ++p) {
        kr[p] = *(const bf16x8*)&Kg[(moff + p * 4 + krow) * 1536 + kin];
        vr[p] = *(const bf16x8*)&Vg[(size_t)(p * 64 + vrow) * 16384 + moff + vin];
      }
    }

    // S = Q K^T : 16x32 per wave
    f32x4 s0 = (f32x4){0.f, 0.f, 0.f, 0.f}, s1 = (f32x4){0.f, 0.f, 0.f, 0.f};
#pragma unroll
    for (int kb = 0; kb < 16; ++kb) {
      bf16x8 b0 = *(const bf16x8*)&Ks[ll * 520 + kb * 32 + kk];
      bf16x8 b1 = *(const bf16x8*)&Ks[(16 + ll) * 520 + kb * 32 + kk];
      s0 = __builtin_amdgcn_mfma_f32_16x16x32_bf16(qf[kb], b0, s0, 0, 0, 0);
      s1 = __builtin_amdgcn_mfma_f32_16x16x32_bf16(qf[kb], b1, s1, 0, 0, 0);
    }

    // T13 defer-max: wave-wide max test; rescale only when max moved > 8
    float wmax = fmaxf(fmaxf(fmaxf(s0[0], s0[1]), fmaxf(s0[2], s0[3])),
                       fmaxf(fmaxf(s1[0], s1[1]), fmaxf(s1[2], s1[3])));
    wmax = fmaxf(wmax, __shfl_xor(wmax, 1));
    wmax = fmaxf(wmax, __shfl_xor(wmax, 2));
    wmax = fmaxf(wmax, __shfl_xor(wmax, 4));
    wmax = fmaxf(wmax, __shfl_xor(wmax, 8));
    wmax = fmaxf(wmax, __shfl_xor(wmax, 16));
    wmax = fmaxf(wmax, __shfl_xor(wmax, 32));
    const float thr = fminf(fminf(mrow[0], mrow[1]), fminf(mrow[2], mrow[3]));
    if (__any(wmax > thr + 8.0f)) {  // slow path (first tile + rare max jumps)
#pragma unroll
      for (int r = 0; r < 4; ++r) {
        float mx = fmaxf(s0[r], s1[r]);
        mx = fmaxf(mx, __shfl_xor(mx, 1));
        mx = fmaxf(mx, __shfl_xor(mx, 2));
        mx = fmaxf(mx, __shfl_xor(mx, 4));
        mx = fmaxf(mx, __shfl_xor(mx, 8));
        const float mn = fmaxf(mrow[r], mx);
        const float alpha = __expf(mrow[r] - mn);
        mrow[r] = mn;
        const float p0 = __expf(s0[r] - mn);
        const float p1 = __expf(s1[r] - mn);
        s0[r] = p0;
        s1[r] = p1;
        lrow[r] = lrow[r] * alpha + (p0 + p1);
#pragma unroll
        for (int f = 0; f < 32; ++f) o[f][r] *= alpha;
      }
    } else {  // fast path: stale max is fine (P bounded by e^8)
#pragma unroll
      for (int r = 0; r < 4; ++r) {
        const float p0 = __expf(s0[r] - mrow[r]);
        const float p1 = __expf(s1[r] - mrow[r]);
        s0[r] = p0;
        s1[r] = p1;
        lrow[r] += p0 + p1;
      }
    }

#pragma unroll
    for (int r = 0; r < 4; ++r) {
      Ps[(lg * 4 + r) * 40 + ll] = f2bf(s0[r]);
      Ps[(lg * 4 + r) * 40 + 16 + ll] = f2bf(s1[r]);
    }

    // PV: O(16x512) += P(16x32) @ V(32x512)
    bf16x8 pa = *(const bf16x8*)&Ps[ll * 40 + kk];
#pragma unroll
    for (int vf = 0; vf < 32; ++vf) {
      bf16x8 vb = *(const bf16x8*)&Vs[(vf * 16 + ll) * 40 + kk];
      o[vf] = __builtin_amdgcn_mfma_f32_16x16x32_bf16(pa, vb, o[vf], 0, 0, 0);
    }
  }

  // reduce l partials across the 16-lane row group
#pragma unroll
  for (int r = 0; r < 4; ++r) {
    float lr = lrow[r];
    lr += __shfl_xor(lr, 1);
    lr += __shfl_xor(lr, 2);
    lr += __shfl_xor(lr, 4);
    lr += __shfl_xor(lr, 8);
    lrow[r] = lr;
  }

  // merge split-KV states: group 1 publishes via LDS (overlays dead K/V buffers)
  __syncthreads();
  float* ex = (float*)smem;          // [4][16][520] f32 = 133,120 B
  float* ml = ex + 4 * 16 * 520;     // [4*16][2]
  if (g == 1) {
#pragma unroll
    for (int vf = 0; vf < 32; ++vf) {
      const int col = vf * 16 + ll;
#pragma unroll
      for (int r = 0; r < 4; ++r)
        ex[(wq * 16 + lg * 4 + r) * 520 + col] = o[vf][r];
    }
    if (ll == 0) {
#pragma unroll
      for (int r = 0; r < 4; ++r) {
        ml[(wq * 16 + lg * 4 + r) * 2 + 0] = mrow[r];
        ml[(wq * 16 + lg * 4 + r) * 2 + 1] = lrow[r];
      }
    }
  }
  __syncthreads();
  if (g == 0) {
    float a0[4], a1[4], rl[4];
#pragma unroll
    for (int r = 0; r < 4; ++r) {
      const int row = wq * 16 + lg * 4 + r;
      const float m1 = ml[row * 2 + 0], l1 = ml[row * 2 + 1];
      const float mm = fmaxf(mrow[r], m1);
      a0[r] = __expf(mrow[r] - mm);
      a1[r] = __expf(m1 - mm);
      rl[r] = 1.0f / (lrow[r] * a0[r] + l1 * a1[r]);
    }
#pragma unroll
    for (int vf = 0; vf < 32; ++vf) {
      const int col = vf * 16 + ll;
#pragma unroll
      for (int r = 0; r < 4; ++r) {
        const size_t row = qrow_base + lg * 4 + r;
        const float ov = o[vf][r] * a0[r] + ex[(wq * 16 + lg * 4 + r) * 520 + col] * a1[r];
        const float val = ov * rl[r] + X[row * 512 + col];
        RES[row * 1536 + 1024 + col] = f2bf(val);
      }
    }
  }
}

// ---------------- GEMM2: out = res @ bf16(Wout) + bout (res strided in qkv v-cols) ----------------
__global__ __launch_bounds__(256) void gemm_out(const unsigned short* __restrict__ A,
                                                const float* __restrict__ W,
                                                const float* __restrict__ bias,
                                                float* __restrict__ OUT) {
  __shared__ __align__(16) unsigned short Asm[64][40];
  __shared__ __align__(16) unsigned short Bsm[64][40];
  const int tid = threadIdx.x;
  const int wave = tid >> 6, lane = tid & 63;
  const int lg = lane >> 4, ll = lane & 15;
  const int kk = lg * 8;
  const int m0 = blockIdx.y * 64, n0 = blockIdx.x * 64;

  f32x4 acc[4];
#pragma unroll
  for (int i = 0; i < 4; ++i) acc[i] = (f32x4){0.f, 0.f, 0.f, 0.f};

  const int arow = wave * 16 + ll;

  for (int kt = 0; kt < 512; kt += 32) {
    {
      const int row = tid >> 2, k0 = (tid & 3) * 8;
      *(bf16x8*)&Asm[row][k0] = *(const bf16x8*)&A[(size_t)(m0 + row) * 1536 + 1024 + kt + k0];
    }
    {
      const int k = tid >> 3, cl = tid & 7;
      const float* src = W + (size_t)(kt + k) * 512 + n0 + cl;
#pragma unroll
      for (int i = 0; i < 8; ++i) Bsm[cl + i * 8][k] = f2bf(src[i * 8]);
    }
    __syncthreads();
    bf16x8 a = *(const bf16x8*)&Asm[arow][kk];
#pragma unroll
    for (int nf = 0; nf < 4; ++nf) {
      bf16x8 b = *(const bf16x8*)&Bsm[nf * 16 + ll][kk];
      acc[nf] = __builtin_amdgcn_mfma_f32_16x16x32_bf16(a, b, acc[nf], 0, 0, 0);
    }
    __syncthreads();
  }
#pragma unroll
  for (int nf = 0; nf < 4; ++nf) {
    const int col = n0 + nf * 16 + ll;
    const float bv = bias[col];
#pragma unroll
    for (int r = 0; r < 4; ++r) {
      const int row = m0 + wave * 16 + lg * 4 + r;
      OUT[(size_t)row * 512 + col] = acc[nf][r] + bv;
    }
  }
}

extern "C" void kernel_launch(void* const* d_in, const int* in_sizes, int n_in,
                              void* d_out, int out_size, void* d_ws, size_t ws_size,
                              hipStream_t stream) {
  const float* x = (const float*)d_in[0];     // [8,2048,512]
  const float* Wqkv = (const float*)d_in[1];  // [512,1536]
  const float* Wout = (const float*)d_in[2];  // [512,512]
  const float* bout = (const float*)d_in[3];  // [512]
  float* out = (float*)d_out;                 // [8,2048,512] fp32

  unsigned short* qkvb = (unsigned short*)d_ws;        // 16384*1536 bf16 = 50.3MB
  unsigned short* VT = qkvb + (size_t)16384 * 1536;    // 512*16384  bf16 = 16.8MB

  gemm_qkv<<<dim3(24, 256), 256, 0, stream>>>(x, Wqkv, qkvb);
  transpose_v<<<dim3(128, 4), 256, 0, stream>>>(qkvb, VT);
  flash_attn<<<dim3(8, 32), 512, 0, stream>>>(qkvb, VT, x, qkvb);
  gemm_out<<<dim3(8, 256), 256, 0, stream>>>(qkvb, Wout, bout, out);
}

// Round 5
// 279.672 us; speedup vs baseline: 3.8403x; 3.8403x over previous
//
#include <hip/hip_runtime.h>
#include <hip/hip_bf16.h>

// MSSA: x(8,2048,512) -> qkv = x@Wqkv ; scores = (q*s)@(k*s)^T over FULL 512 dims ;
// attn = softmax ; out = attn@v ; result = (out + x)@Wout + bout
//
// Two paths chosen by ws_size:
//  BIG (>=128MiB): materialized-S 3-pass attention (S-GEMM -> softmax -> PV-GEMM),
//                  every kernel a high-occupancy tiled GEMM.
//  SMALL: R2 flash fallback (known-good, 237us attn).
// Workspace:
//   qkvb : bf16 [16384][1536]  q(scaled 0.125) | k(scaled) | v ; v-cols dead after
//                              transpose_v -> reused to hold res = bf16(attn_out + x)
//   VT   : bf16 [512][16384]   V transposed (d-major)
//   S    : bf16 [8][2048][2048] scores -> (in-place) softmax P   [BIG path only]
//
// LESSON (R3/R4): 512-thread blocks cap unified regs at 256/wave -> unavoidable
// spill for this per-wave state. Keep 256-thread blocks.

typedef __attribute__((ext_vector_type(8))) short bf16x8;
typedef __attribute__((ext_vector_type(4))) float f32x4;

__device__ __forceinline__ unsigned short f2bf(float f) {
  unsigned u = __builtin_bit_cast(unsigned, f);
  u += 0x7fffu + ((u >> 16) & 1u);   // RNE
  return (unsigned short)(u >> 16);
}
__device__ __forceinline__ float bf2f(unsigned short h) {
  unsigned u = ((unsigned)h) << 16;
  return __builtin_bit_cast(float, u);
}

// ---------------- GEMM1: qkv = bf16(x) @ bf16(Wqkv), scale q,k cols by 0.125 ----------------
__global__ __launch_bounds__(256) void gemm_qkv(const float* __restrict__ X,
                                                const float* __restrict__ W,
                                                unsigned short* __restrict__ QKV) {
  __shared__ __align__(16) unsigned short Asm[64][40];
  __shared__ __align__(16) unsigned short Bsm[64][40];
  const int tid = threadIdx.x;
  const int wave = tid >> 6, lane = tid & 63;
  const int lg = lane >> 4, ll = lane & 15;
  const int kk = lg * 8;
  const int m0 = blockIdx.y * 64, n0 = blockIdx.x * 64;

  f32x4 acc[4];
#pragma unroll
  for (int i = 0; i < 4; ++i) acc[i] = (f32x4){0.f, 0.f, 0.f, 0.f};

  const int arow = wave * 16 + ll;

  for (int kt = 0; kt < 512; kt += 32) {
    {
      const int row = tid >> 2, k0 = (tid & 3) * 8;
      const float* src = X + (size_t)(m0 + row) * 512 + kt + k0;
      bf16x8 v;
#pragma unroll
      for (int i = 0; i < 8; ++i) v[i] = (short)f2bf(src[i]);
      *(bf16x8*)&Asm[row][k0] = v;
    }
    {
      const int k = tid >> 3, cl = tid & 7;
      const float* src = W + (size_t)(kt + k) * 1536 + n0 + cl;
#pragma unroll
      for (int i = 0; i < 8; ++i) Bsm[cl + i * 8][k] = f2bf(src[i * 8]);
    }
    __syncthreads();
    bf16x8 a = *(const bf16x8*)&Asm[arow][kk];
#pragma unroll
    for (int nf = 0; nf < 4; ++nf) {
      bf16x8 b = *(const bf16x8*)&Bsm[nf * 16 + ll][kk];
      acc[nf] = __builtin_amdgcn_mfma_f32_16x16x32_bf16(a, b, acc[nf], 0, 0, 0);
    }
    __syncthreads();
  }
#pragma unroll
  for (int nf = 0; nf < 4; ++nf) {
    const int col = n0 + nf * 16 + ll;
    const float scl = (col < 1024) ? 0.125f : 1.0f;
#pragma unroll
    for (int r = 0; r < 4; ++r) {
      const int row = m0 + wave * 16 + lg * 4 + r;
      QKV[(size_t)row * 1536 + col] = f2bf(acc[nf][r] * scl);
    }
  }
}

// ---------------- Transpose V: VT[d][m] = qkv[m][1024+d] ----------------
__global__ __launch_bounds__(256) void transpose_v(const unsigned short* __restrict__ QKV,
                                                   unsigned short* __restrict__ VT) {
  const int t = threadIdx.x;
  const int m0 = blockIdx.x * 128 + (t & 15) * 8;
  const int d0 = blockIdx.y * 128 + (t >> 4) * 8;
  bf16x8 r[8];
#pragma unroll
  for (int j = 0; j < 8; ++j)
    r[j] = *(const bf16x8*)&QKV[(size_t)(m0 + j) * 1536 + 1024 + d0];
#pragma unroll
  for (int i = 0; i < 8; ++i) {
    bf16x8 o;
#pragma unroll
    for (int j = 0; j < 8; ++j) o[j] = r[j][i];
    *(bf16x8*)&VT[(size_t)(d0 + i) * 16384 + m0] = o;
  }
}

// ======== BIG path: 128x128-tile GEMMs (4 waves, 4x4 16x16x32 frags, padded LDS) ========

// S[b][q][kv] = Q[b][q][:] . K[b][kv][:]   (both already scaled by 0.125)
__global__ __launch_bounds__(256) void sgemm128(const unsigned short* __restrict__ QKV,
                                                unsigned short* __restrict__ S) {
  __shared__ __align__(16) unsigned short Asm[128][40];
  __shared__ __align__(16) unsigned short Bsm[128][40];
  const int tid = threadIdx.x;
  const int wave = tid >> 6, lane = tid & 63;
  const int wr = wave >> 1, wc = wave & 1;   // 2x2 wave quadrants of 64x64
  const int lg = lane >> 4, ll = lane & 15;
  const int kk = lg * 8;
  const int bid = blockIdx.x;
  const int b = bid & 7;          // batch -> XCD (L2 locality for Q/K panels)
  const int idx = bid >> 3;
  const int kvt = idx & 15, qt = idx >> 4;

  const int srow = tid >> 1, sk = (tid & 1) * 16;  // stage: 128 rows x 32 k, 16 elem/thread
  const unsigned short* Ag = QKV + ((size_t)b * 2048 + qt * 128) * 1536;        // q cols
  const unsigned short* Bg = QKV + ((size_t)b * 2048 + kvt * 128) * 1536 + 512; // k cols

  bf16x8 ar0 = *(const bf16x8*)&Ag[(size_t)srow * 1536 + sk];
  bf16x8 ar1 = *(const bf16x8*)&Ag[(size_t)srow * 1536 + sk + 8];
  bf16x8 br0 = *(const bf16x8*)&Bg[(size_t)srow * 1536 + sk];
  bf16x8 br1 = *(const bf16x8*)&Bg[(size_t)srow * 1536 + sk + 8];

  f32x4 acc[4][4];
#pragma unroll
  for (int i = 0; i < 4; ++i)
#pragma unroll
    for (int j = 0; j < 4; ++j) acc[i][j] = (f32x4){0.f, 0.f, 0.f, 0.f};

  for (int kt = 0; kt < 512; kt += 32) {
    __syncthreads();  // previous tile's reads done
    *(bf16x8*)&Asm[srow][sk] = ar0;
    *(bf16x8*)&Asm[srow][sk + 8] = ar1;
    *(bf16x8*)&Bsm[srow][sk] = br0;
    *(bf16x8*)&Bsm[srow][sk + 8] = br1;
    __syncthreads();
    if (kt < 480) {  // prefetch next K-step; hides under MFMA
      ar0 = *(const bf16x8*)&Ag[(size_t)srow * 1536 + kt + 32 + sk];
      ar1 = *(const bf16x8*)&Ag[(size_t)srow * 1536 + kt + 32 + sk + 8];
      br0 = *(const bf16x8*)&Bg[(size_t)srow * 1536 + kt + 32 + sk];
      br1 = *(const bf16x8*)&Bg[(size_t)srow * 1536 + kt + 32 + sk + 8];
    }
    bf16x8 af[4], bfr[4];
#pragma unroll
    for (int ai = 0; ai < 4; ++ai) af[ai] = *(const bf16x8*)&Asm[wr * 64 + ai * 16 + ll][kk];
#pragma unroll
    for (int bj = 0; bj < 4; ++bj) bfr[bj] = *(const bf16x8*)&Bsm[wc * 64 + bj * 16 + ll][kk];
#pragma unroll
    for (int ai = 0; ai < 4; ++ai)
#pragma unroll
      for (int bj = 0; bj < 4; ++bj)
        acc[ai][bj] = __builtin_amdgcn_mfma_f32_16x16x32_bf16(af[ai], bfr[bj], acc[ai][bj], 0, 0, 0);
  }
  unsigned short* Sg = S + (size_t)b * 2048 * 2048;
#pragma unroll
  for (int ai = 0; ai < 4; ++ai)
#pragma unroll
    for (int bj = 0; bj < 4; ++bj) {
      const int col = kvt * 128 + wc * 64 + bj * 16 + ll;
#pragma unroll
      for (int r = 0; r < 4; ++r) {
        const int row = qt * 128 + wr * 64 + ai * 16 + lg * 4 + r;
        Sg[(size_t)row * 2048 + col] = f2bf(acc[ai][bj][r]);
      }
    }
}

// in-place row softmax over 2048 bf16 (one block per row)
__global__ __launch_bounds__(256) void softmax_rows(unsigned short* __restrict__ S) {
  __shared__ float red[8];
  const int tid = threadIdx.x;
  const int wave = tid >> 6, lane = tid & 63;
  unsigned short* row = S + (size_t)blockIdx.x * 2048;

  bf16x8 v = *(const bf16x8*)&row[tid * 8];
  float f[8];
#pragma unroll
  for (int j = 0; j < 8; ++j) f[j] = bf2f((unsigned short)v[j]);

  float mx = f[0];
#pragma unroll
  for (int j = 1; j < 8; ++j) mx = fmaxf(mx, f[j]);
  mx = fmaxf(mx, __shfl_xor(mx, 1));
  mx = fmaxf(mx, __shfl_xor(mx, 2));
  mx = fmaxf(mx, __shfl_xor(mx, 4));
  mx = fmaxf(mx, __shfl_xor(mx, 8));
  mx = fmaxf(mx, __shfl_xor(mx, 16));
  mx = fmaxf(mx, __shfl_xor(mx, 32));
  if (lane == 0) red[wave] = mx;
  __syncthreads();
  mx = fmaxf(fmaxf(red[0], red[1]), fmaxf(red[2], red[3]));

  float s = 0.f;
#pragma unroll
  for (int j = 0; j < 8; ++j) {
    f[j] = __expf(f[j] - mx);
    s += f[j];
  }
  s += __shfl_xor(s, 1);
  s += __shfl_xor(s, 2);
  s += __shfl_xor(s, 4);
  s += __shfl_xor(s, 8);
  s += __shfl_xor(s, 16);
  s += __shfl_xor(s, 32);
  if (lane == 0) red[4 + wave] = s;
  __syncthreads();
  s = (red[4] + red[5]) + (red[6] + red[7]);
  const float inv = 1.0f / s;
#pragma unroll
  for (int j = 0; j < 8; ++j) v[j] = (short)f2bf(f[j] * inv);
  *(bf16x8*)&row[tid * 8] = v;
}

// res = P @ V + x  (A = P rows stride 2048, B from VT; epilogue residual, store to qkv v-cols)
__global__ __launch_bounds__(256) void pvgemm128(const unsigned short* __restrict__ P,
                                                 const unsigned short* __restrict__ VT,
                                                 const float* __restrict__ X,
                                                 unsigned short* __restrict__ RES) {
  __shared__ __align__(16) unsigned short Asm[128][40];
  __shared__ __align__(16) unsigned short Bsm[128][40];
  const int tid = threadIdx.x;
  const int wave = tid >> 6, lane = tid & 63;
  const int wr = wave >> 1, wc = wave & 1;
  const int lg = lane >> 4, ll = lane & 15;
  const int kk = lg * 8;
  const int bid = blockIdx.x;
  const int b = bid & 7;
  const int idx = bid >> 3;
  const int dt = idx & 3, qt = idx >> 2;  // 4 d-tiles share P-tile in L2 (same XCD, adjacent)

  const int srow = tid >> 1, sk = (tid & 1) * 16;
  const unsigned short* Ag = P + (size_t)b * 2048 * 2048 + (size_t)(qt * 128) * 2048;
  const unsigned short* Bg = VT + (size_t)(dt * 128) * 16384 + (size_t)b * 2048;

  bf16x8 ar0 = *(const bf16x8*)&Ag[(size_t)srow * 2048 + sk];
  bf16x8 ar1 = *(const bf16x8*)&Ag[(size_t)srow * 2048 + sk + 8];
  bf16x8 br0 = *(const bf16x8*)&Bg[(size_t)srow * 16384 + sk];
  bf16x8 br1 = *(const bf16x8*)&Bg[(size_t)srow * 16384 + sk + 8];

  f32x4 acc[4][4];
#pragma unroll
  for (int i = 0; i < 4; ++i)
#pragma unroll
    for (int j = 0; j < 4; ++j) acc[i][j] = (f32x4){0.f, 0.f, 0.f, 0.f};

  for (int kt = 0; kt < 2048; kt += 32) {
    __syncthreads();
    *(bf16x8*)&Asm[srow][sk] = ar0;
    *(bf16x8*)&Asm[srow][sk + 8] = ar1;
    *(bf16x8*)&Bsm[srow][sk] = br0;
    *(bf16x8*)&Bsm[srow][sk + 8] = br1;
    __syncthreads();
    if (kt < 2016) {
      ar0 = *(const bf16x8*)&Ag[(size_t)srow * 2048 + kt + 32 + sk];
      ar1 = *(const bf16x8*)&Ag[(size_t)srow * 2048 + kt + 32 + sk + 8];
      br0 = *(const bf16x8*)&Bg[(size_t)srow * 16384 + kt + 32 + sk];
      br1 = *(const bf16x8*)&Bg[(size_t)srow * 16384 + kt + 32 + sk + 8];
    }
    bf16x8 af[4], bfr[4];
#pragma unroll
    for (int ai = 0; ai < 4; ++ai) af[ai] = *(const bf16x8*)&Asm[wr * 64 + ai * 16 + ll][kk];
#pragma unroll
    for (int bj = 0; bj < 4; ++bj) bfr[bj] = *(const bf16x8*)&Bsm[wc * 64 + bj * 16 + ll][kk];
#pragma unroll
    for (int ai = 0; ai < 4; ++ai)
#pragma unroll
      for (int bj = 0; bj < 4; ++bj)
        acc[ai][bj] = __builtin_amdgcn_mfma_f32_16x16x32_bf16(af[ai], bfr[bj], acc[ai][bj], 0, 0, 0);
  }
#pragma unroll
  for (int ai = 0; ai < 4; ++ai)
#pragma unroll
    for (int bj = 0; bj < 4; ++bj) {
      const int col = dt * 128 + wc * 64 + bj * 16 + ll;
#pragma unroll
      for (int r = 0; r < 4; ++r) {
        const size_t row = (size_t)b * 2048 + qt * 128 + wr * 64 + ai * 16 + lg * 4 + r;
        const float val = acc[ai][bj][r] + X[row * 512 + col];
        RES[row * 1536 + 1024 + col] = f2bf(val);
      }
    }
}

// ======== SMALL-ws fallback: R2 flash attention (known-good) ========
__global__ __launch_bounds__(256) void flash_attn(const unsigned short* __restrict__ QKV,
                                                  const unsigned short* __restrict__ VT,
                                                  const float* __restrict__ X,
                                                  unsigned short* __restrict__ RES) {
  __shared__ __align__(16) unsigned short Ksm[32][520];
  __shared__ __align__(16) unsigned short Vsm[512][40];
  __shared__ __align__(16) unsigned short Psm[4][16][40];
  const int tid = threadIdx.x;
  const int wave = tid >> 6, lane = tid & 63;
  const int lg = lane >> 4, ll = lane & 15;
  const int kk = lg * 8;
  const int b = blockIdx.x, qt = blockIdx.y;
  const size_t qrow_base = (size_t)b * 2048 + qt * 64 + wave * 16;

  bf16x8 qf[16];
  {
    const size_t row = qrow_base + ll;
#pragma unroll
    for (int kb = 0; kb < 16; ++kb)
      qf[kb] = *(const bf16x8*)&QKV[row * 1536 + kb * 32 + kk];
  }
  const int krow = tid >> 6, kin = (tid & 63) * 8;
  const int vrow = tid >> 2, vin = (tid & 3) * 8;
  const unsigned short* Kg = QKV + ((size_t)b * 2048) * 1536 + 512;
  const unsigned short* Vg = VT + (size_t)b * 2048;

  bf16x8 kr[8], vr[8];
#pragma unroll
  for (int p = 0; p < 8; ++p) {
    kr[p] = *(const bf16x8*)&Kg[(size_t)(p * 4 + krow) * 1536 + kin];
    vr[p] = *(const bf16x8*)&Vg[(size_t)(p * 64 + vrow) * 16384 + vin];
  }
  f32x4 o[32];
#pragma unroll
  for (int i = 0; i < 32; ++i) o[i] = (f32x4){0.f, 0.f, 0.f, 0.f};
  float mrow[4] = {-1e30f, -1e30f, -1e30f, -1e30f};
  float lrow[4] = {0.f, 0.f, 0.f, 0.f};

  for (int mt = 0; mt < 64; ++mt) {
    __syncthreads();
#pragma unroll
    for (int p = 0; p < 8; ++p) {
      *(bf16x8*)&Ksm[p * 4 + krow][kin] = kr[p];
      *(bf16x8*)&Vsm[p * 64 + vrow][vin] = vr[p];
    }
    __syncthreads();
    if (mt < 63) {
      const size_t moff = (size_t)(mt + 1) * 32;
#pragma unroll
      for (int p = 0; p < 8; ++p) {
        kr[p] = *(const bf16x8*)&Kg[(moff + p * 4 + krow) * 1536 + kin];
        vr[p] = *(const bf16x8*)&Vg[(size_t)(p * 64 + vrow) * 16384 + moff + vin];
      }
    }
    f32x4 s0 = (f32x4){0.f, 0.f, 0.f, 0.f}, s1 = (f32x4){0.f, 0.f, 0.f, 0.f};
#pragma unroll
    for (int kb = 0; kb < 16; ++kb) {
      bf16x8 b0 = *(const bf16x8*)&Ksm[ll][kb * 32 + kk];
      bf16x8 b1 = *(const bf16x8*)&Ksm[16 + ll][kb * 32 + kk];
      s0 = __builtin_amdgcn_mfma_f32_16x16x32_bf16(qf[kb], b0, s0, 0, 0, 0);
      s1 = __builtin_amdgcn_mfma_f32_16x16x32_bf16(qf[kb], b1, s1, 0, 0, 0);
    }
    float alpha[4];
#pragma unroll
    for (int r = 0; r < 4; ++r) {
      float mx = fmaxf(s0[r], s1[r]);
      mx = fmaxf(mx, __shfl_xor(mx, 1));
      mx = fmaxf(mx, __shfl_xor(mx, 2));
      mx = fmaxf(mx, __shfl_xor(mx, 4));
      mx = fmaxf(mx, __shfl_xor(mx, 8));
      const float mn = fmaxf(mrow[r], mx);
      alpha[r] = __expf(mrow[r] - mn);
      mrow[r] = mn;
      const float p0 = __expf(s0[r] - mn);
      const float p1 = __expf(s1[r] - mn);
      s0[r] = p0;
      s1[r] = p1;
      float rs = p0 + p1;
      rs += __shfl_xor(rs, 1);
      rs += __shfl_xor(rs, 2);
      rs += __shfl_xor(rs, 4);
      rs += __shfl_xor(rs, 8);
      lrow[r] = lrow[r] * alpha[r] + rs;
    }
#pragma unroll
    for (int r = 0; r < 4; ++r) {
      Psm[wave][lg * 4 + r][ll] = f2bf(s0[r]);
      Psm[wave][lg * 4 + r][16 + ll] = f2bf(s1[r]);
    }
    const bool need = (alpha[0] < 1.f) || (alpha[1] < 1.f) || (alpha[2] < 1.f) || (alpha[3] < 1.f);
    if (__any(need)) {
#pragma unroll
      for (int f = 0; f < 32; ++f) {
        o[f][0] *= alpha[0];
        o[f][1] *= alpha[1];
        o[f][2] *= alpha[2];
        o[f][3] *= alpha[3];
      }
    }
    bf16x8 pa = *(const bf16x8*)&Psm[wave][ll][kk];
#pragma unroll
    for (int vf = 0; vf < 32; ++vf) {
      bf16x8 vb = *(const bf16x8*)&Vsm[vf * 16 + ll][kk];
      o[vf] = __builtin_amdgcn_mfma_f32_16x16x32_bf16(pa, vb, o[vf], 0, 0, 0);
    }
  }
  float rl[4];
#pragma unroll
  for (int r = 0; r < 4; ++r) rl[r] = 1.0f / lrow[r];
#pragma unroll
  for (int vf = 0; vf < 32; ++vf) {
    const int col = vf * 16 + ll;
#pragma unroll
    for (int r = 0; r < 4; ++r) {
      const size_t row = qrow_base + lg * 4 + r;
      const float val = o[vf][r] * rl[r] + X[row * 512 + col];
      RES[row * 1536 + 1024 + col] = f2bf(val);
    }
  }
}

// ---------------- GEMM2: out = res @ bf16(Wout) + bout (res strided in qkv v-cols) ----------------
__global__ __launch_bounds__(256) void gemm_out(const unsigned short* __restrict__ A,
                                                const float* __restrict__ W,
                                                const float* __restrict__ bias,
                                                float* __restrict__ OUT) {
  __shared__ __align__(16) unsigned short Asm[64][40];
  __shared__ __align__(16) unsigned short Bsm[64][40];
  const int tid = threadIdx.x;
  const int wave = tid >> 6, lane = tid & 63;
  const int lg = lane >> 4, ll = lane & 15;
  const int kk = lg * 8;
  const int m0 = blockIdx.y * 64, n0 = blockIdx.x * 64;

  f32x4 acc[4];
#pragma unroll
  for (int i = 0; i < 4; ++i) acc[i] = (f32x4){0.f, 0.f, 0.f, 0.f};

  const int arow = wave * 16 + ll;

  for (int kt = 0; kt < 512; kt += 32) {
    {
      const int row = tid >> 2, k0 = (tid & 3) * 8;
      *(bf16x8*)&Asm[row][k0] = *(const bf16x8*)&A[(size_t)(m0 + row) * 1536 + 1024 + kt + k0];
    }
    {
      const int k = tid >> 3, cl = tid & 7;
      const float* src = W + (size_t)(kt + k) * 512 + n0 + cl;
#pragma unroll
      for (int i = 0; i < 8; ++i) Bsm[cl + i * 8][k] = f2bf(src[i * 8]);
    }
    __syncthreads();
    bf16x8 a = *(const bf16x8*)&Asm[arow][kk];
#pragma unroll
    for (int nf = 0; nf < 4; ++nf) {
      bf16x8 b = *(const bf16x8*)&Bsm[nf * 16 + ll][kk];
      acc[nf] = __builtin_amdgcn_mfma_f32_16x16x32_bf16(a, b, acc[nf], 0, 0, 0);
    }
    __syncthreads();
  }
#pragma unroll
  for (int nf = 0; nf < 4; ++nf) {
    const int col = n0 + nf * 16 + ll;
    const float bv = bias[col];
#pragma unroll
    for (int r = 0; r < 4; ++r) {
      const int row = m0 + wave * 16 + lg * 4 + r;
      OUT[(size_t)row * 512 + col] = acc[nf][r] + bv;
    }
  }
}

extern "C" void kernel_launch(void* const* d_in, const int* in_sizes, int n_in,
                              void* d_out, int out_size, void* d_ws, size_t ws_size,
                              hipStream_t stream) {
  const float* x = (const float*)d_in[0];     // [8,2048,512]
  const float* Wqkv = (const float*)d_in[1];  // [512,1536]
  const float* Wout = (const float*)d_in[2];  // [512,512]
  const float* bout = (const float*)d_in[3];  // [512]
  float* out = (float*)d_out;                 // [8,2048,512] fp32

  unsigned short* qkvb = (unsigned short*)d_ws;        // 16384*1536 bf16 = 50.3MB
  unsigned short* VT = qkvb + (size_t)16384 * 1536;    // 512*16384  bf16 = 16.8MB
  unsigned short* S = VT + (size_t)512 * 16384;        // 8*2048*2048 bf16 = 67.1MB (BIG only)
  const bool big = ws_size >= (size_t)134217728;       // 128 MiB

  gemm_qkv<<<dim3(24, 256), 256, 0, stream>>>(x, Wqkv, qkvb);
  transpose_v<<<dim3(128, 4), 256, 0, stream>>>(qkvb, VT);
  if (big) {
    sgemm128<<<2048, 256, 0, stream>>>(qkvb, S);
    softmax_rows<<<16384, 256, 0, stream>>>(S);
    pvgemm128<<<512, 256, 0, stream>>>(S, VT, x, qkvb);
  } else {
    flash_attn<<<dim3(8, 32), 256, 0, stream>>>(qkvb, VT, x, qkvb);
  }
  gemm_out<<<dim3(8, 256), 256, 0, stream>>>(qkvb, Wout, bout, out);
}

// Round 6
// 209.236 us; speedup vs baseline: 5.1331x; 1.3366x over previous
//
#include <hip/hip_runtime.h>
#include <hip/hip_bf16.h>

// MSSA: x(8,2048,512) -> qkv = x@Wqkv ; scores = (q*s)@(k*s)^T over FULL 512 dims ;
// attn = softmax ; out = attn@v ; result = (out + x)@Wout + bout
//
// All GEMMs use the 128x128-tile bf16 MFMA template (4 waves, 4x4 16x16x32 frags).
// Workspace = exactly 128 MiB (ws >= 128MiB proven in R5):
//   qkvb : bf16 [16384][1536]  q(scaled 0.125)|k(scaled)|v ; v-cols dead after
//                              transpose_v -> reused for res = bf16(attn_out + x);
//   VT   : bf16 [512][16384]   V transposed; dead after pvgemm -> reused for WoutT
//   S    : bf16 [8][2048][2048] scores/P. Before sgemm128 writes it, its space
//                              holds xb (bf16 X, 16.8MB) + WT (Wqkv^T scaled, 1.5MB).
//
// LESSONS: R3/R4 512-thr blocks cap regs at 256/wave -> spill. R5: 64^2-tile GEMM
// with in-loop fp32 transpose staging = 190 TF; 128^2 pure-bf16 template is the fix.

typedef __attribute__((ext_vector_type(8))) short bf16x8;
typedef __attribute__((ext_vector_type(4))) float f32x4;

__device__ __forceinline__ unsigned short f2bf(float f) {
  unsigned u = __builtin_bit_cast(unsigned, f);
  u += 0x7fffu + ((u >> 16) & 1u);   // RNE
  return (unsigned short)(u >> 16);
}
__device__ __forceinline__ float bf2f(unsigned short h) {
  unsigned u = ((unsigned)h) << 16;
  return __builtin_bit_cast(float, u);
}

// ---------------- prep_x: xb = bf16(X), 16 elems/thread ----------------
__global__ __launch_bounds__(256) void prep_x(const float* __restrict__ X,
                                              unsigned short* __restrict__ XB) {
  const size_t base = ((size_t)blockIdx.x * 256 + threadIdx.x) * 16;
  f32x4 a0 = *(const f32x4*)&X[base];
  f32x4 a1 = *(const f32x4*)&X[base + 4];
  f32x4 a2 = *(const f32x4*)&X[base + 8];
  f32x4 a3 = *(const f32x4*)&X[base + 12];
  bf16x8 o0, o1;
#pragma unroll
  for (int j = 0; j < 4; ++j) {
    o0[j] = (short)f2bf(a0[j]);
    o0[4 + j] = (short)f2bf(a1[j]);
    o1[j] = (short)f2bf(a2[j]);
    o1[4 + j] = (short)f2bf(a3[j]);
  }
  *(bf16x8*)&XB[base] = o0;
  *(bf16x8*)&XB[base + 8] = o1;
}

// ---------------- prep_w: WT[c][k] = bf16(Wqkv[k][c] * (c<1024 ? 0.125 : 1)) ----------------
__global__ __launch_bounds__(256) void prep_w(const float* __restrict__ W,
                                              unsigned short* __restrict__ WT) {
  const int t = threadIdx.x;
  const int c0 = blockIdx.x * 128 + (t & 15) * 8;
  const int k0 = blockIdx.y * 128 + (t >> 4) * 8;
  float r[8][8];
#pragma unroll
  for (int j = 0; j < 8; ++j) {
    f32x4 lo = *(const f32x4*)&W[(size_t)(k0 + j) * 1536 + c0];
    f32x4 hi = *(const f32x4*)&W[(size_t)(k0 + j) * 1536 + c0 + 4];
#pragma unroll
    for (int q = 0; q < 4; ++q) {
      r[j][q] = lo[q];
      r[j][4 + q] = hi[q];
    }
  }
#pragma unroll
  for (int i = 0; i < 8; ++i) {
    const float scl = (c0 + i < 1024) ? 0.125f : 1.0f;
    bf16x8 o;
#pragma unroll
    for (int j = 0; j < 8; ++j) o[j] = (short)f2bf(r[j][i] * scl);
    *(bf16x8*)&WT[(size_t)(c0 + i) * 512 + k0] = o;
  }
}

// ---------------- transpose_wout: WoutT[c][k] = bf16(Wout[k][c]) ----------------
__global__ __launch_bounds__(256) void transpose_wout(const float* __restrict__ W,
                                                      unsigned short* __restrict__ WT) {
  const int t = threadIdx.x;
  const int c0 = blockIdx.x * 128 + (t & 15) * 8;
  const int k0 = blockIdx.y * 128 + (t >> 4) * 8;
  float r[8][8];
#pragma unroll
  for (int j = 0; j < 8; ++j) {
    f32x4 lo = *(const f32x4*)&W[(size_t)(k0 + j) * 512 + c0];
    f32x4 hi = *(const f32x4*)&W[(size_t)(k0 + j) * 512 + c0 + 4];
#pragma unroll
    for (int q = 0; q < 4; ++q) {
      r[j][q] = lo[q];
      r[j][4 + q] = hi[q];
    }
  }
#pragma unroll
  for (int i = 0; i < 8; ++i) {
    bf16x8 o;
#pragma unroll
    for (int j = 0; j < 8; ++j) o[j] = (short)f2bf(r[j][i]);
    *(bf16x8*)&WT[(size_t)(c0 + i) * 512 + k0] = o;
  }
}

// ---------------- Transpose V: VT[d][m] = qkv[m][1024+d] ----------------
__global__ __launch_bounds__(256) void transpose_v(const unsigned short* __restrict__ QKV,
                                                   unsigned short* __restrict__ VT) {
  const int t = threadIdx.x;
  const int m0 = blockIdx.x * 128 + (t & 15) * 8;
  const int d0 = blockIdx.y * 128 + (t >> 4) * 8;
  bf16x8 r[8];
#pragma unroll
  for (int j = 0; j < 8; ++j)
    r[j] = *(const bf16x8*)&QKV[(size_t)(m0 + j) * 1536 + 1024 + d0];
#pragma unroll
  for (int i = 0; i < 8; ++i) {
    bf16x8 o;
#pragma unroll
    for (int j = 0; j < 8; ++j) o[j] = r[j][i];
    *(bf16x8*)&VT[(size_t)(d0 + i) * 16384 + m0] = o;
  }
}

// ======== 128x128-tile GEMM template kernels (4 waves, 4x4 16x16x32 frags, padded LDS) ========

// qkv = xb @ WT^T  (both bf16, k-contiguous; scale pre-folded into WT)
__global__ __launch_bounds__(256) void gemm_qkv128(const unsigned short* __restrict__ XB,
                                                   const unsigned short* __restrict__ WT,
                                                   unsigned short* __restrict__ QKV) {
  __shared__ __align__(16) unsigned short Asm[128][40];
  __shared__ __align__(16) unsigned short Bsm[128][40];
  const int tid = threadIdx.x;
  const int wave = tid >> 6, lane = tid & 63;
  const int wr = wave >> 1, wc = wave & 1;
  const int lg = lane >> 4, ll = lane & 15;
  const int kk = lg * 8;
  const int bid = blockIdx.x;
  const int qt = bid / 12, nt = bid - qt * 12;

  const int srow = tid >> 1, sk = (tid & 1) * 16;
  const unsigned short* Ag = XB + (size_t)(qt * 128) * 512;
  const unsigned short* Bg = WT + (size_t)(nt * 128) * 512;

  bf16x8 ar0 = *(const bf16x8*)&Ag[(size_t)srow * 512 + sk];
  bf16x8 ar1 = *(const bf16x8*)&Ag[(size_t)srow * 512 + sk + 8];
  bf16x8 br0 = *(const bf16x8*)&Bg[(size_t)srow * 512 + sk];
  bf16x8 br1 = *(const bf16x8*)&Bg[(size_t)srow * 512 + sk + 8];

  f32x4 acc[4][4];
#pragma unroll
  for (int i = 0; i < 4; ++i)
#pragma unroll
    for (int j = 0; j < 4; ++j) acc[i][j] = (f32x4){0.f, 0.f, 0.f, 0.f};

  for (int kt = 0; kt < 512; kt += 32) {
    __syncthreads();
    *(bf16x8*)&Asm[srow][sk] = ar0;
    *(bf16x8*)&Asm[srow][sk + 8] = ar1;
    *(bf16x8*)&Bsm[srow][sk] = br0;
    *(bf16x8*)&Bsm[srow][sk + 8] = br1;
    __syncthreads();
    if (kt < 480) {
      ar0 = *(const bf16x8*)&Ag[(size_t)srow * 512 + kt + 32 + sk];
      ar1 = *(const bf16x8*)&Ag[(size_t)srow * 512 + kt + 32 + sk + 8];
      br0 = *(const bf16x8*)&Bg[(size_t)srow * 512 + kt + 32 + sk];
      br1 = *(const bf16x8*)&Bg[(size_t)srow * 512 + kt + 32 + sk + 8];
    }
    bf16x8 af[4], bfr[4];
#pragma unroll
    for (int ai = 0; ai < 4; ++ai) af[ai] = *(const bf16x8*)&Asm[wr * 64 + ai * 16 + ll][kk];
#pragma unroll
    for (int bj = 0; bj < 4; ++bj) bfr[bj] = *(const bf16x8*)&Bsm[wc * 64 + bj * 16 + ll][kk];
#pragma unroll
    for (int ai = 0; ai < 4; ++ai)
#pragma unroll
      for (int bj = 0; bj < 4; ++bj)
        acc[ai][bj] = __builtin_amdgcn_mfma_f32_16x16x32_bf16(af[ai], bfr[bj], acc[ai][bj], 0, 0, 0);
  }
#pragma unroll
  for (int ai = 0; ai < 4; ++ai)
#pragma unroll
    for (int bj = 0; bj < 4; ++bj) {
      const int col = nt * 128 + wc * 64 + bj * 16 + ll;
#pragma unroll
      for (int r = 0; r < 4; ++r) {
        const int row = qt * 128 + wr * 64 + ai * 16 + lg * 4 + r;
        QKV[(size_t)row * 1536 + col] = f2bf(acc[ai][bj][r]);
      }
    }
}

// S[b][q][kv] = Q[b][q][:] . K[b][kv][:]   (both already scaled by 0.125)
__global__ __launch_bounds__(256) void sgemm128(const unsigned short* __restrict__ QKV,
                                                unsigned short* __restrict__ S) {
  __shared__ __align__(16) unsigned short Asm[128][40];
  __shared__ __align__(16) unsigned short Bsm[128][40];
  const int tid = threadIdx.x;
  const int wave = tid >> 6, lane = tid & 63;
  const int wr = wave >> 1, wc = wave & 1;
  const int lg = lane >> 4, ll = lane & 15;
  const int kk = lg * 8;
  const int bid = blockIdx.x;
  const int b = bid & 7;          // batch -> XCD (L2 locality)
  const int idx = bid >> 3;
  const int kvt = idx & 15, qt = idx >> 4;

  const int srow = tid >> 1, sk = (tid & 1) * 16;
  const unsigned short* Ag = QKV + ((size_t)b * 2048 + qt * 128) * 1536;
  const unsigned short* Bg = QKV + ((size_t)b * 2048 + kvt * 128) * 1536 + 512;

  bf16x8 ar0 = *(const bf16x8*)&Ag[(size_t)srow * 1536 + sk];
  bf16x8 ar1 = *(const bf16x8*)&Ag[(size_t)srow * 1536 + sk + 8];
  bf16x8 br0 = *(const bf16x8*)&Bg[(size_t)srow * 1536 + sk];
  bf16x8 br1 = *(const bf16x8*)&Bg[(size_t)srow * 1536 + sk + 8];

  f32x4 acc[4][4];
#pragma unroll
  for (int i = 0; i < 4; ++i)
#pragma unroll
    for (int j = 0; j < 4; ++j) acc[i][j] = (f32x4){0.f, 0.f, 0.f, 0.f};

  for (int kt = 0; kt < 512; kt += 32) {
    __syncthreads();
    *(bf16x8*)&Asm[srow][sk] = ar0;
    *(bf16x8*)&Asm[srow][sk + 8] = ar1;
    *(bf16x8*)&Bsm[srow][sk] = br0;
    *(bf16x8*)&Bsm[srow][sk + 8] = br1;
    __syncthreads();
    if (kt < 480) {
      ar0 = *(const bf16x8*)&Ag[(size_t)srow * 1536 + kt + 32 + sk];
      ar1 = *(const bf16x8*)&Ag[(size_t)srow * 1536 + kt + 32 + sk + 8];
      br0 = *(const bf16x8*)&Bg[(size_t)srow * 1536 + kt + 32 + sk];
      br1 = *(const bf16x8*)&Bg[(size_t)srow * 1536 + kt + 32 + sk + 8];
    }
    bf16x8 af[4], bfr[4];
#pragma unroll
    for (int ai = 0; ai < 4; ++ai) af[ai] = *(const bf16x8*)&Asm[wr * 64 + ai * 16 + ll][kk];
#pragma unroll
    for (int bj = 0; bj < 4; ++bj) bfr[bj] = *(const bf16x8*)&Bsm[wc * 64 + bj * 16 + ll][kk];
#pragma unroll
    for (int ai = 0; ai < 4; ++ai)
#pragma unroll
      for (int bj = 0; bj < 4; ++bj)
        acc[ai][bj] = __builtin_amdgcn_mfma_f32_16x16x32_bf16(af[ai], bfr[bj], acc[ai][bj], 0, 0, 0);
  }
  unsigned short* Sg = S + (size_t)b * 2048 * 2048;
#pragma unroll
  for (int ai = 0; ai < 4; ++ai)
#pragma unroll
    for (int bj = 0; bj < 4; ++bj) {
      const int col = kvt * 128 + wc * 64 + bj * 16 + ll;
#pragma unroll
      for (int r = 0; r < 4; ++r) {
        const int row = qt * 128 + wr * 64 + ai * 16 + lg * 4 + r;
        Sg[(size_t)row * 2048 + col] = f2bf(acc[ai][bj][r]);
      }
    }
}

// in-place row softmax over 2048 bf16 (one block per row)
__global__ __launch_bounds__(256) void softmax_rows(unsigned short* __restrict__ S) {
  __shared__ float red[8];
  const int tid = threadIdx.x;
  const int wave = tid >> 6, lane = tid & 63;
  unsigned short* row = S + (size_t)blockIdx.x * 2048;

  bf16x8 v = *(const bf16x8*)&row[tid * 8];
  float f[8];
#pragma unroll
  for (int j = 0; j < 8; ++j) f[j] = bf2f((unsigned short)v[j]);

  float mx = f[0];
#pragma unroll
  for (int j = 1; j < 8; ++j) mx = fmaxf(mx, f[j]);
  mx = fmaxf(mx, __shfl_xor(mx, 1));
  mx = fmaxf(mx, __shfl_xor(mx, 2));
  mx = fmaxf(mx, __shfl_xor(mx, 4));
  mx = fmaxf(mx, __shfl_xor(mx, 8));
  mx = fmaxf(mx, __shfl_xor(mx, 16));
  mx = fmaxf(mx, __shfl_xor(mx, 32));
  if (lane == 0) red[wave] = mx;
  __syncthreads();
  mx = fmaxf(fmaxf(red[0], red[1]), fmaxf(red[2], red[3]));

  float s = 0.f;
#pragma unroll
  for (int j = 0; j < 8; ++j) {
    f[j] = __expf(f[j] - mx);
    s += f[j];
  }
  s += __shfl_xor(s, 1);
  s += __shfl_xor(s, 2);
  s += __shfl_xor(s, 4);
  s += __shfl_xor(s, 8);
  s += __shfl_xor(s, 16);
  s += __shfl_xor(s, 32);
  if (lane == 0) red[4 + wave] = s;
  __syncthreads();
  s = (red[4] + red[5]) + (red[6] + red[7]);
  const float inv = 1.0f / s;
#pragma unroll
  for (int j = 0; j < 8; ++j) v[j] = (short)f2bf(f[j] * inv);
  *(bf16x8*)&row[tid * 8] = v;
}

// res = P @ V + x  (A = P rows stride 2048, B from VT; epilogue residual, store to qkv v-cols)
__global__ __launch_bounds__(256) void pvgemm128(const unsigned short* __restrict__ P,
                                                 const unsigned short* __restrict__ VT,
                                                 const float* __restrict__ X,
                                                 unsigned short* __restrict__ RES) {
  __shared__ __align__(16) unsigned short Asm[128][40];
  __shared__ __align__(16) unsigned short Bsm[128][40];
  const int tid = threadIdx.x;
  const int wave = tid >> 6, lane = tid & 63;
  const int wr = wave >> 1, wc = wave & 1;
  const int lg = lane >> 4, ll = lane & 15;
  const int kk = lg * 8;
  const int bid = blockIdx.x;
  const int b = bid & 7;
  const int idx = bid >> 3;
  const int dt = idx & 3, qt = idx >> 2;

  const int srow = tid >> 1, sk = (tid & 1) * 16;
  const unsigned short* Ag = P + (size_t)b * 2048 * 2048 + (size_t)(qt * 128) * 2048;
  const unsigned short* Bg = VT + (size_t)(dt * 128) * 16384 + (size_t)b * 2048;

  bf16x8 ar0 = *(const bf16x8*)&Ag[(size_t)srow * 2048 + sk];
  bf16x8 ar1 = *(const bf16x8*)&Ag[(size_t)srow * 2048 + sk + 8];
  bf16x8 br0 = *(const bf16x8*)&Bg[(size_t)srow * 16384 + sk];
  bf16x8 br1 = *(const bf16x8*)&Bg[(size_t)srow * 16384 + sk + 8];

  f32x4 acc[4][4];
#pragma unroll
  for (int i = 0; i < 4; ++i)
#pragma unroll
    for (int j = 0; j < 4; ++j) acc[i][j] = (f32x4){0.f, 0.f, 0.f, 0.f};

  for (int kt = 0; kt < 2048; kt += 32) {
    __syncthreads();
    *(bf16x8*)&Asm[srow][sk] = ar0;
    *(bf16x8*)&Asm[srow][sk + 8] = ar1;
    *(bf16x8*)&Bsm[srow][sk] = br0;
    *(bf16x8*)&Bsm[srow][sk + 8] = br1;
    __syncthreads();
    if (kt < 2016) {
      ar0 = *(const bf16x8*)&Ag[(size_t)srow * 2048 + kt + 32 + sk];
      ar1 = *(const bf16x8*)&Ag[(size_t)srow * 2048 + kt + 32 + sk + 8];
      br0 = *(const bf16x8*)&Bg[(size_t)srow * 16384 + kt + 32 + sk];
      br1 = *(const bf16x8*)&Bg[(size_t)srow * 16384 + kt + 32 + sk + 8];
    }
    bf16x8 af[4], bfr[4];
#pragma unroll
    for (int ai = 0; ai < 4; ++ai) af[ai] = *(const bf16x8*)&Asm[wr * 64 + ai * 16 + ll][kk];
#pragma unroll
    for (int bj = 0; bj < 4; ++bj) bfr[bj] = *(const bf16x8*)&Bsm[wc * 64 + bj * 16 + ll][kk];
#pragma unroll
    for (int ai = 0; ai < 4; ++ai)
#pragma unroll
      for (int bj = 0; bj < 4; ++bj)
        acc[ai][bj] = __builtin_amdgcn_mfma_f32_16x16x32_bf16(af[ai], bfr[bj], acc[ai][bj], 0, 0, 0);
  }
#pragma unroll
  for (int ai = 0; ai < 4; ++ai)
#pragma unroll
    for (int bj = 0; bj < 4; ++bj) {
      const int col = dt * 128 + wc * 64 + bj * 16 + ll;
#pragma unroll
      for (int r = 0; r < 4; ++r) {
        const size_t row = (size_t)b * 2048 + qt * 128 + wr * 64 + ai * 16 + lg * 4 + r;
        const float val = acc[ai][bj][r] + X[row * 512 + col];
        RES[row * 1536 + 1024 + col] = f2bf(val);
      }
    }
}

// out = res @ WoutT^T + bout (res strided in qkv v-cols; WoutT k-contiguous)
__global__ __launch_bounds__(256) void gemm_out128(const unsigned short* __restrict__ A,
                                                   const unsigned short* __restrict__ WT,
                                                   const float* __restrict__ bias,
                                                   float* __restrict__ OUT) {
  __shared__ __align__(16) unsigned short Asm[128][40];
  __shared__ __align__(16) unsigned short Bsm[128][40];
  const int tid = threadIdx.x;
  const int wave = tid >> 6, lane = tid & 63;
  const int wr = wave >> 1, wc = wave & 1;
  const int lg = lane >> 4, ll = lane & 15;
  const int kk = lg * 8;
  const int bid = blockIdx.x;
  const int dt = bid & 3, qt = bid >> 2;

  const int srow = tid >> 1, sk = (tid & 1) * 16;
  const unsigned short* Ag = A + (size_t)(qt * 128) * 1536 + 1024;
  const unsigned short* Bg = WT + (size_t)(dt * 128) * 512;

  bf16x8 ar0 = *(const bf16x8*)&Ag[(size_t)srow * 1536 + sk];
  bf16x8 ar1 = *(const bf16x8*)&Ag[(size_t)srow * 1536 + sk + 8];
  bf16x8 br0 = *(const bf16x8*)&Bg[(size_t)srow * 512 + sk];
  bf16x8 br1 = *(const bf16x8*)&Bg[(size_t)srow * 512 + sk + 8];

  f32x4 acc[4][4];
#pragma unroll
  for (int i = 0; i < 4; ++i)
#pragma unroll
    for (int j = 0; j < 4; ++j) acc[i][j] = (f32x4){0.f, 0.f, 0.f, 0.f};

  for (int kt = 0; kt < 512; kt += 32) {
    __syncthreads();
    *(bf16x8*)&Asm[srow][sk] = ar0;
    *(bf16x8*)&Asm[srow][sk + 8] = ar1;
    *(bf16x8*)&Bsm[srow][sk] = br0;
    *(bf16x8*)&Bsm[srow][sk + 8] = br1;
    __syncthreads();
    if (kt < 480) {
      ar0 = *(const bf16x8*)&Ag[(size_t)srow * 1536 + kt + 32 + sk];
      ar1 = *(const bf16x8*)&Ag[(size_t)srow * 1536 + kt + 32 + sk + 8];
      br0 = *(const bf16x8*)&Bg[(size_t)srow * 512 + kt + 32 + sk];
      br1 = *(const bf16x8*)&Bg[(size_t)srow * 512 + kt + 32 + sk + 8];
    }
    bf16x8 af[4], bfr[4];
#pragma unroll
    for (int ai = 0; ai < 4; ++ai) af[ai] = *(const bf16x8*)&Asm[wr * 64 + ai * 16 + ll][kk];
#pragma unroll
    for (int bj = 0; bj < 4; ++bj) bfr[bj] = *(const bf16x8*)&Bsm[wc * 64 + bj * 16 + ll][kk];
#pragma unroll
    for (int ai = 0; ai < 4; ++ai)
#pragma unroll
      for (int bj = 0; bj < 4; ++bj)
        acc[ai][bj] = __builtin_amdgcn_mfma_f32_16x16x32_bf16(af[ai], bfr[bj], acc[ai][bj], 0, 0, 0);
  }
#pragma unroll
  for (int ai = 0; ai < 4; ++ai)
#pragma unroll
    for (int bj = 0; bj < 4; ++bj) {
      const int col = dt * 128 + wc * 64 + bj * 16 + ll;
      const float bv = bias[col];
#pragma unroll
      for (int r = 0; r < 4; ++r) {
        const int row = qt * 128 + wr * 64 + ai * 16 + lg * 4 + r;
        OUT[(size_t)row * 512 + col] = acc[ai][bj][r] + bv;
      }
    }
}

extern "C" void kernel_launch(void* const* d_in, const int* in_sizes, int n_in,
                              void* d_out, int out_size, void* d_ws, size_t ws_size,
                              hipStream_t stream) {
  const float* x = (const float*)d_in[0];     // [8,2048,512]
  const float* Wqkv = (const float*)d_in[1];  // [512,1536]
  const float* Wout = (const float*)d_in[2];  // [512,512]
  const float* bout = (const float*)d_in[3];  // [512]
  float* out = (float*)d_out;                 // [8,2048,512] fp32

  unsigned short* qkvb = (unsigned short*)d_ws;        // 16384*1536 bf16 = 50.3MB
  unsigned short* VT = qkvb + (size_t)16384 * 1536;    // 512*16384  bf16 = 16.8MB
  unsigned short* S = VT + (size_t)512 * 16384;        // 8*2048*2048 bf16 = 67.1MB
  // transient aliases (dead before/after the kernels that use them):
  unsigned short* xb = S;                              // bf16 X, dead before sgemm128
  unsigned short* WT = S + (size_t)16384 * 512;        // Wqkv^T scaled, dead before sgemm128
  unsigned short* WoutT = VT;                          // VT dead after pvgemm128

  prep_x<<<2048, 256, 0, stream>>>(x, xb);
  prep_w<<<dim3(12, 4), 256, 0, stream>>>(Wqkv, WT);
  gemm_qkv128<<<1536, 256, 0, stream>>>(xb, WT, qkvb);
  transpose_v<<<dim3(128, 4), 256, 0, stream>>>(qkvb, VT);
  sgemm128<<<2048, 256, 0, stream>>>(qkvb, S);
  softmax_rows<<<16384, 256, 0, stream>>>(S);
  pvgemm128<<<512, 256, 0, stream>>>(S, VT, x, qkvb);
  transpose_wout<<<dim3(4, 4), 256, 0, stream>>>(Wout, WoutT);
  gemm_out128<<<512, 256, 0, stream>>>(qkvb, WoutT, bout, out);
}